// Round 11
// baseline (101.631 us; speedup 1.0000x reference)
//
#include <hip/hip_runtime.h>
#include <math.h>

#define EPS 1e-6f

typedef __attribute__((ext_vector_type(4))) float f32x4;

constexpr int B    = 8;
constexpr int F    = 64;
constexpr int C    = 16;
constexpr int L    = 65536;      // 256*256
constexpr int G4   = L / 4;      // float4 elements per (b, f) slice
constexpr int TPB  = 256;
constexpr int NREP = 8;          // atomic-target replicas

// Stage 1: partials num[b,c] = sum_l (e2 - 2*dot)*r, den[b,c] = sum_l r.
// ws layout: float ws[NREP][2][2][B][C] -> [rep][term][num/den][b][c]
//
// R9/R10 lesson: hand-counted vmcnt asm is unverifiable here (two NaNs).
// This round: NO manual waits anywhere — correctness is entirely compiler-
// managed. The load-batch shape is instead forced by T19 sched_group_barrier
// (compile-time interleave directive): per f-batch, emit 4 VMEM reads FIRST,
// then the 80-FMA VALU block. The compiler still inserts its own (correct)
// waitcnts, so worst case the hint is ignored and we get R5-level perf.
// 4-way c-split keeps accumulators at dot[4][4]+e2[4]=20 regs; float4 loads
// double R5's bytes-in-flight per wave. ~50 VGPR < the (256,8) 64-cap.
__global__ __launch_bounds__(TPB, 8)
void cross_partial_kernel(const float* __restrict__ embed1,
                          const float* __restrict__ rids1,
                          const float* __restrict__ embed2,
                          const float* __restrict__ rids2,
                          const float* __restrict__ codebook,
                          float* __restrict__ ws)
{
    const int tid  = threadIdx.x;
    const int lane = tid & 63;
    const int wid  = tid >> 6;
    const int term = blockIdx.z;       // 0: (embed_1, r_ids_2), 1: (embed_2, r_ids_1)
    const int b    = blockIdx.y;
    const float* eptr = (term == 0) ? embed1 : embed2;
    const float* rptr = (term == 0) ? rids2  : rids1;

    // wave-uniform c-base in an SGPR: codebook reads scalarize (s_load)
    const int c0 = __builtin_amdgcn_readfirstlane(wid * 4);

    const int lbase = blockIdx.x * 256;    // 64 lanes x float4 = 256 floats
    const f32x4* eb = (const f32x4*)(eptr + (size_t)b * F * L + lbase) + lane;
    const f32x4* rb = (const f32x4*)(rptr + (size_t)b * C * L + lbase) + lane;

    float dot[4][4], e2[4];
    #pragma unroll
    for (int j = 0; j < 4; ++j) {
        e2[j] = 0.f;
        #pragma unroll
        for (int k = 0; k < 4; ++k) dot[j][k] = 0.f;
    }

    #pragma unroll 1
    for (int fb = 0; fb < F; fb += 4) {
        f32x4 ev[4];
        #pragma unroll
        for (int u = 0; u < 4; ++u)
            ev[u] = eb[(size_t)(fb + u) * G4];
        #pragma unroll
        for (int u = 0; u < 4; ++u) {
            #pragma unroll
            for (int k = 0; k < 4; ++k)
                e2[k] = fmaf(ev[u][k], ev[u][k], e2[k]);
            #pragma unroll
            for (int j = 0; j < 4; ++j) {
                const float wv = codebook[(fb + u) * C + c0 + j];  // SGPR bcast
                #pragma unroll
                for (int k = 0; k < 4; ++k)
                    dot[j][k] = fmaf(ev[u][k], wv, dot[j][k]);
            }
        }
        // T19: pin the emitted shape — 4 global loads first, then the FMA
        // block. Dependency-safe: compiler still inserts its own waitcnts.
        __builtin_amdgcn_sched_group_barrier(0x020, 4, 0);   // VMEM_READ x4
        __builtin_amdgcn_sched_group_barrier(0x002, 84, 0);  // VALU block
    }

    // epilogue: 4 r float4 loads, fold, wave shuffle-reduce, direct atomics
    f32x4 rv[4];
    #pragma unroll
    for (int j = 0; j < 4; ++j)
        rv[j] = rb[(size_t)(c0 + j) * G4];

    const int rep = blockIdx.x & (NREP - 1);
    float* wsn = ws + ((((size_t)rep * 2 + term) * 2 + 0) * B + b) * C;
    float* wsd = ws + ((((size_t)rep * 2 + term) * 2 + 1) * B + b) * C;
    #pragma unroll
    for (int j = 0; j < 4; ++j) {
        float num = fmaf(-2.f, dot[j][0], e2[0]) * rv[j][0]
                  + fmaf(-2.f, dot[j][1], e2[1]) * rv[j][1]
                  + fmaf(-2.f, dot[j][2], e2[2]) * rv[j][2]
                  + fmaf(-2.f, dot[j][3], e2[3]) * rv[j][3];
        float den = (rv[j][0] + rv[j][1]) + (rv[j][2] + rv[j][3]);
        #pragma unroll
        for (int off = 32; off > 0; off >>= 1) {
            num += __shfl_down(num, off, 64);
            den += __shfl_down(den, off, 64);
        }
        if (lane == 0) {
            atomicAdd(&wsn[c0 + j], num);
            atomicAdd(&wsd[c0 + j], den);
        }
    }
}

// Stage 2: single block. cross = (num + cb2[c]*den)/(den+EPS); plus dist/reg losses.
__global__ __launch_bounds__(256)
void finalize_kernel(const float* __restrict__ codebook,
                     const float* __restrict__ ws,
                     float* __restrict__ out)
{
    __shared__ float cbs[F * C];
    __shared__ float cb2[C];
    __shared__ float red[256];
    __shared__ float redv[256];
    const int tid = threadIdx.x;
    ((float4*)cbs)[tid] = ((const float4*)codebook)[tid];
    __syncthreads();
    if (tid < C) {
        float s = 0.f;
        for (int f = 0; f < F; ++f) { const float v = cbs[f * C + tid]; s = fmaf(v, v, s); }
        cb2[tid] = s;
    }
    __syncthreads();

    // l_cross: 256 entries = [term(2)][b(8)][c(16)]
    {
        const int term = tid >> 7, rem = tid & 127;
        const int b = rem >> 4, c = rem & 15;
        float num = 0.f, den = 0.f;
        for (int rep = 0; rep < NREP; ++rep) {
            num += ws[((((size_t)rep * 2 + term) * 2 + 0) * B + b) * C + c];
            den += ws[((((size_t)rep * 2 + term) * 2 + 1) * B + b) * C + c];
        }
        const bool valid = (den != 0.f);
        red[tid]  = valid ? (num + cb2[c] * den) / (den + EPS) : 0.f;
        redv[tid] = valid ? 1.f : 0.f;
    }
    __syncthreads();
    if (tid == 0) {
        float s0 = 0.f, n0 = 0.f, s1 = 0.f, n1 = 0.f;
        for (int i = 0;   i < 128; ++i) { s0 += red[i]; n0 += redv[i]; }
        for (int i = 128; i < 256; ++i) { s1 += red[i]; n1 += redv[i]; }
        out[0] = s0 / n0 + s1 / n1;
    }
    __syncthreads();

    // l_dist: 256 (ci,cj) pairs, diagonal included exactly as reference
    {
        const int ci = tid & 15, cj = tid >> 4;
        float sq = 0.f;
        for (int f = 0; f < F; ++f) {
            const float d = cbs[f * C + ci] - cbs[f * C + cj];
            sq = fmaf(d, d, sq);
        }
        const float dist = (sq > 0.f) ? sqrtf(sq) : 0.f;
        const float h = fmaxf(2.f * 1.0f - dist, 0.f);
        red[tid] = h * h;
    }
    __syncthreads();
    if (tid == 0) {
        float s = 0.f;
        for (int i = 0; i < 256; ++i) s += red[i];
        out[1] = s / (2.f * C * (C - 1));
        float rg = 0.f;
        for (int c = 0; c < C; ++c) rg += sqrtf(cb2[c]);
        out[2] = rg / C;
    }
}

extern "C" void kernel_launch(void* const* d_in, const int* in_sizes, int n_in,
                              void* d_out, int out_size, void* d_ws, size_t ws_size,
                              hipStream_t stream)
{
    const float* e1 = (const float*)d_in[0];
    const float* r1 = (const float*)d_in[1];
    const float* e2 = (const float*)d_in[2];
    const float* r2 = (const float*)d_in[3];
    const float* cb = (const float*)d_in[4];
    float* out = (float*)d_out;
    float* ws  = (float*)d_ws;

    // zero the NREP*2*2*B*C accumulator block (16 KB)
    hipMemsetAsync(ws, 0, (size_t)NREP * 2 * 2 * B * C * sizeof(float), stream);

    dim3 grid(L / 256, B, 2);   // 256 x 8 x 2 = 4096 blocks, 4 waves each
    cross_partial_kernel<<<grid, TPB, 0, stream>>>(e1, r1, e2, r2, cb, ws);
    finalize_kernel<<<1, 256, 0, stream>>>(cb, ws, out);
}